// Round 5
// baseline (526.802 us; speedup 1.0000x reference)
//
#include <hip/hip_runtime.h>
#include <math.h>

#define BB 2
#define CC 512
#define HH 30
#define WW 40
#define KK 64
#define NPIX (HH*WW)
#define HP 27
#define WP 37
#define NP (HP*WP)
#define LEPS 1e-12f

#define PADW 172      // xn ring row stride in floats (4*40 + 12 pad -> 12-bank row shift)
#define NCG 8         // c-groups (64 c each)

// ---------------------------------------------------------------------------
// Kernel 1: per-(b,h) row: channel L2-norm, xn store, logits (K=64) + softmax.
// ---------------------------------------------------------------------------
__global__ __launch_bounds__(512) void k_norm_soft(
    const float* __restrict__ x, const float* __restrict__ convw,
    float* __restrict__ xn, float* __restrict__ soft)
{
  const int h = blockIdx.x, b = blockIdx.y;
  const int t = threadIdx.x;
  __shared__ float xc[64][41];
  __shared__ float cw[64][65];
  __shared__ float Lb[KK][WW + 1];
  __shared__ float psum[12][WW];
  __shared__ float invn[WW];
  __shared__ float mx[WW], Zs[WW];

  const size_t xbase = (size_t)b * CC * NPIX + (size_t)h * WW;

  if (t < 480) {
    const int w = t % 40, part = t / 40;
    float s = 0.f;
    for (int c = part; c < CC; c += 12) {
      const float v = x[xbase + (size_t)c * NPIX + w];
      s = fmaf(v, v, s);
    }
    psum[part][w] = s;
  }
  __syncthreads();
  if (t < 40) {
    float s = 0.f;
    #pragma unroll
    for (int p = 0; p < 12; ++p) s += psum[p][t];
    invn[t] = 1.f / fmaxf(sqrtf(s), LEPS);
  }
  __syncthreads();

  const int k = t & 63, wp = t >> 6;
  float acc[5] = {0.f, 0.f, 0.f, 0.f, 0.f};
  for (int cb = 0; cb < CC; cb += 64) {
    #pragma unroll
    for (int n = 0; n < 5; ++n) {
      const int idx = t + 512 * n;
      const int c = idx / 40, w = idx % 40;
      const float v = x[xbase + (size_t)(cb + c) * NPIX + w] * invn[w];
      xc[c][w] = v;
      xn[xbase + (size_t)(cb + c) * NPIX + w] = v;
    }
    #pragma unroll
    for (int n = 0; n < 8; ++n) {
      const int idx = t + 512 * n;
      const int kk2 = idx >> 6, c2 = idx & 63;
      cw[kk2][c2] = convw[(size_t)kk2 * CC + cb + c2];
    }
    __syncthreads();
    #pragma unroll 1
    for (int c = 0; c < 64; ++c) {
      const float cv = cw[k][c];
      #pragma unroll
      for (int n = 0; n < 5; ++n)
        acc[n] = fmaf(cv, xc[c][wp + 8 * n], acc[n]);
    }
    __syncthreads();
  }
  #pragma unroll
  for (int n = 0; n < 5; ++n) Lb[k][wp + 8 * n] = acc[n];
  __syncthreads();
  if (t < 40) {
    float m = -1e30f;
    for (int kk2 = 0; kk2 < KK; ++kk2) m = fmaxf(m, Lb[kk2][t]);
    float Z = 0.f;
    for (int kk2 = 0; kk2 < KK; ++kk2) Z += expf(Lb[kk2][t] - m);
    mx[t] = m; Zs[t] = Z;
  }
  __syncthreads();
  const size_t sbase = (size_t)b * KK * NPIX + (size_t)h * WW;
  #pragma unroll
  for (int n = 0; n < 5; ++n) {
    const int idx = t + 512 * n;
    const int kk2 = idx / 40, w = idx % 40;
    soft[sbase + (size_t)kk2 * NPIX + w] = expf(Lb[kk2][w] - mx[w]) / Zs[w];
  }
}

// ---------------------------------------------------------------------------
// Kernel G: per-(b,k) global VLAD row, first L2 norm over c.
// ---------------------------------------------------------------------------
__global__ __launch_bounds__(256) void k_global(
    const float* __restrict__ xn, const float* __restrict__ soft,
    const float* __restrict__ cent, float* __restrict__ ghat)
{
  const int k = blockIdx.x, b = blockIdx.y, t = threadIdx.x;
  __shared__ float sb[NPIX];
  __shared__ float red[256];
  const float* srow = soft + ((size_t)b * KK + k) * NPIX;
  for (int i2 = t; i2 < NPIX; i2 += 256) sb[i2] = srow[i2];
  __syncthreads();
  float p = 0.f;
  for (int i2 = t; i2 < NPIX; i2 += 256) p += sb[i2];
  red[t] = p;
  __syncthreads();
  for (int s = 128; s > 0; s >>= 1) { if (t < s) red[t] += red[t + s]; __syncthreads(); }
  const float Sg = red[0];
  __syncthreads();

  const int c0 = t, c1 = t + 256;
  const float* x0 = xn + ((size_t)b * CC + c0) * NPIX;
  const float* x1 = xn + ((size_t)b * CC + c1) * NPIX;
  float a0 = 0.f, a1 = 0.f;
  for (int p4 = 0; p4 < NPIX; p4 += 4) {
    const float4 s4 = *(const float4*)&sb[p4];
    const float4 v0 = *(const float4*)(x0 + p4);
    const float4 v1 = *(const float4*)(x1 + p4);
    a0 = fmaf(s4.x, v0.x, a0); a0 = fmaf(s4.y, v0.y, a0);
    a0 = fmaf(s4.z, v0.z, a0); a0 = fmaf(s4.w, v0.w, a0);
    a1 = fmaf(s4.x, v1.x, a1); a1 = fmaf(s4.y, v1.y, a1);
    a1 = fmaf(s4.z, v1.z, a1); a1 = fmaf(s4.w, v1.w, a1);
  }
  const float g0 = a0 - cent[(size_t)k * CC + c0] * Sg;
  const float g1 = a1 - cent[(size_t)k * CC + c1] * Sg;
  red[t] = g0 * g0 + g1 * g1;
  __syncthreads();
  for (int s = 128; s > 0; s >>= 1) { if (t < s) red[t] += red[t + s]; __syncthreads(); }
  const float inv = 1.f / fmaxf(sqrtf(red[0]), LEPS);
  float* gr = ghat + ((size_t)b * KK + k) * CC;
  gr[c0] = g0 * inv; gr[c1] = g1 * inv;
}

__global__ __launch_bounds__(256) void k_global2(
    const float* __restrict__ ghat, float* __restrict__ outg)
{
  const int b = blockIdx.x, t = threadIdx.x;
  __shared__ float red[256];
  const float* gb = ghat + (size_t)b * KK * CC;
  float p = 0.f;
  for (int i2 = t; i2 < KK * CC; i2 += 256) { const float v = gb[i2]; p = fmaf(v, v, p); }
  red[t] = p;
  __syncthreads();
  for (int s = 128; s > 0; s >>= 1) { if (t < s) red[t] += red[t + s]; __syncthreads(); }
  const float inv = 1.f / fmaxf(sqrtf(red[0]), LEPS);
  for (int i2 = t; i2 < KK * CC; i2 += 256)
    outg[(size_t)b * KK * CC + i2] = gb[i2] * inv;
}

// ---------------------------------------------------------------------------
// Kernel L v6: block = (cg 64c, kgrp 8k, b x i-quarter). Thread t = c8 + 8*j;
// per-thread tile 8c x 8k x 1j (c = c0 + cc*8 + c8 -> consecutive-row lanes,
// 12-bank row shift via PADW=172 -> uniform 2-way = free; soft reads are
// 8-lane broadcasts). 4-slot xn ring, reg prefetch of row i+4 (v5 discipline).
// Soft slab (10 rows) resident. ssq reduced over c8 via 3x shfl_xor.
// PHASE 0: sp partials; PHASE 1: raw * fs -> out.
// ---------------------------------------------------------------------------
template<int PHASE>
__global__ __launch_bounds__(320, 4) void k_local3(
    const float* __restrict__ xn, const float* __restrict__ soft,
    const float* __restrict__ cent, float* __restrict__ sp,
    const float* __restrict__ fs, float* __restrict__ out)
{
  const int cg = blockIdx.x;             // 0..7 (64 c)
  const int kgrp = blockIdx.y;           // 0..7 (8 k)
  const int bz = blockIdx.z;             // b*4 + iq
  const int b = bz >> 2, iq = bz & 3;
  const int i0 = iq * 7;
  const int n_i = (iq == 3) ? 6 : 7;
  const int k0 = kgrp * 8, c0 = cg * 64;
  const int t = threadIdx.x;
  const int c8 = t & 7, j = t >> 3;      // 8 c-lanes x 40 j

  __shared__ float xn_l[64][PADW];       // 44032 B, ring 4 slots x 40 + pad
  __shared__ float soft_l[8][408];       // 13056 B, 10 rows x 40 + pad
  __shared__ float cent_l[8][64];        //  2048 B

  // stage soft slab rows i0..i0+9 (clamped)
  for (int u = t; u < 8 * 400; u += 320) {
    const int kk = u / 400, rw = u - kk * 400;
    int row = i0 + rw / 40; if (row > HH - 1) row = HH - 1;
    soft_l[kk][rw] = soft[((size_t)(b * KK + k0 + kk)) * NPIX
                          + (size_t)row * 40 + (rw % 40)];
  }
  for (int u = t; u < 512; u += 320)
    cent_l[u >> 6][u & 63] = cent[(size_t)(k0 + (u >> 6)) * CC + c0 + (u & 63)];

  const int sc = t / 10, sq = t % 10;
  #pragma unroll
  for (int rr = 0; rr < 4; ++rr) {
    const int row = i0 + rr;
    const int slot = (row & 3) * 40 + sq * 4;
    *(float4*)&xn_l[sc][slot] =
      *(const float4*)&xn[((size_t)(b * CC + c0 + sc)) * NPIX + (size_t)row * 40 + sq * 4];
    *(float4*)&xn_l[sc + 32][slot] =
      *(const float4*)&xn[((size_t)(b * CC + c0 + sc + 32)) * NPIX + (size_t)row * 40 + sq * 4];
  }
  __syncthreads();

  for (int ii = 0; ii < n_i; ++ii) {
    const int i = i0 + ii;

    // prefetch row i+4 into registers (ds-written after barrier 1)
    const int nrow = (i + 4 < HH) ? (i + 4) : (HH - 1);
    const float4 st0 = *(const float4*)&xn[((size_t)(b * CC + c0 + sc)) * NPIX
                                           + (size_t)nrow * 40 + sq * 4];
    const float4 st1 = *(const float4*)&xn[((size_t)(b * CC + c0 + sc + 32)) * NPIX
                                           + (size_t)nrow * 40 + sq * 4];
    float fsv[8];
    if (PHASE == 1) {
      #pragma unroll
      for (int kk = 0; kk < 8; ++kk)
        fsv[kk] = (j < WP)
          ? fs[((size_t)(b * KK + k0 + kk)) * NP + (size_t)i * WP + j] : 0.f;
    }

    // ---- compute: 8c x 8k, 16 taps ----
    float acc[8][8];
    float Ssum[8];
    #pragma unroll
    for (int cc = 0; cc < 8; ++cc)
      #pragma unroll
      for (int kk = 0; kk < 8; ++kk) acc[cc][kk] = 0.f;
    #pragma unroll
    for (int kk = 0; kk < 8; ++kk) Ssum[kk] = 0.f;

    #pragma unroll
    for (int r = 0; r < 4; ++r) {
      const int xo = ((i + r) & 3) * 40 + j;
      const int so = (ii + r) * 40 + j;
      #pragma unroll
      for (int dx = 0; dx < 4; ++dx) {
        float sv[8], xv[8];
        #pragma unroll
        for (int kk = 0; kk < 8; ++kk) {
          sv[kk] = soft_l[kk][so + dx];
          Ssum[kk] += sv[kk];
        }
        #pragma unroll
        for (int cc = 0; cc < 8; ++cc)
          xv[cc] = xn_l[cc * 8 + c8][xo + dx];
        #pragma unroll
        for (int cc = 0; cc < 8; ++cc)
          #pragma unroll
          for (int kk = 0; kk < 8; ++kk)
            acc[cc][kk] = fmaf(xv[cc], sv[kk], acc[cc][kk]);
      }
    }

    // ---- epilogue ----
    if (PHASE == 0) {
      #pragma unroll
      for (int kk = 0; kk < 8; ++kk) {
        float s = 0.f;
        #pragma unroll
        for (int cc = 0; cc < 8; ++cc) {
          const float raw = fmaf(-cent_l[kk][cc * 8 + c8], Ssum[kk], acc[cc][kk]);
          s = fmaf(raw, raw, s);
        }
        s += __shfl_xor(s, 1, 64);
        s += __shfl_xor(s, 2, 64);
        s += __shfl_xor(s, 4, 64);
        if (c8 == 0 && j < WP)
          sp[(((size_t)(b * KK + k0 + kk)) * NCG + cg) * NP + (size_t)i * WP + j] = s;
      }
    } else if (j < WP) {
      #pragma unroll
      for (int kk = 0; kk < 8; ++kk) {
        #pragma unroll
        for (int cc = 0; cc < 8; ++cc) {
          const float raw = fmaf(-cent_l[kk][cc * 8 + c8], Ssum[kk], acc[cc][kk]);
          out[((size_t)((b * KK + k0 + kk) * CC + c0 + cc * 8 + c8)) * NP
              + (size_t)i * WP + j] = raw * fsv[kk];
        }
      }
    }

    __syncthreads();   // barrier 1: ring slot (i&3) free
    {
      const int slot = ((i + 4) & 3) * 40 + sq * 4;
      *(float4*)&xn_l[sc][slot] = st0;
      *(float4*)&xn_l[sc + 32][slot] = st1;
    }
    __syncthreads();   // barrier 2: new row visible
  }
}

// ---------------------------------------------------------------------------
// Kernel NF_a: sum the NCG per-c-group partials -> ssq. Wide grid, coalesced.
// ---------------------------------------------------------------------------
__global__ __launch_bounds__(256) void k_nf_a(
    const float* __restrict__ sp, float* __restrict__ ssq)
{
  const int u = blockIdx.x * 256 + threadIdx.x;
  if (u >= BB * KK * NP) return;
  const int bk = u / NP, p = u - bk * NP;
  float s = 0.f;
  #pragma unroll
  for (int g = 0; g < NCG; ++g)
    s += sp[((size_t)bk * NCG + g) * NP + p];
  ssq[u] = s;
}

// ---------------------------------------------------------------------------
// Kernel NF_b: per (b, 4 pixels): k-parallel scale build with 64-way LDS
// reduce for the cross-k second norm.
// ---------------------------------------------------------------------------
__global__ __launch_bounds__(256) void k_nf_b(
    const float* __restrict__ ssq, float* __restrict__ fs)
{
  const int b = blockIdx.y, t = threadIdx.x;
  const int k = t >> 2, dp = t & 3;
  const int p = blockIdx.x * 4 + dp;
  __shared__ float red[64][4];
  __shared__ float inv2s[4];
  const bool ok = p < NP;
  const float sr = ok ? ssq[((size_t)(b * KK + k)) * NP + p] : 0.f;
  const float iv = 1.f / fmaxf(sqrtf(sr) * 0.0625f, LEPS);
  red[k][dp] = sr * (1.f / 256.f) * iv * iv;
  __syncthreads();
  if (t < 4) {
    float s = 0.f;
    #pragma unroll
    for (int kk = 0; kk < 64; ++kk) s += red[kk][t];
    inv2s[t] = 1.f / fmaxf(sqrtf(s), LEPS);
  }
  __syncthreads();
  if (ok)
    fs[((size_t)(b * KK + k)) * NP + p] = 0.0625f * iv * inv2s[dp];
}

// ---------------------------------------------------------------------------
extern "C" void kernel_launch(void* const* d_in, const int* in_sizes, int n_in,
                              void* d_out, int out_size, void* d_ws, size_t ws_size,
                              hipStream_t stream)
{
  const float* x     = (const float*)d_in[0];
  const float* convw = (const float*)d_in[1];
  const float* cent  = (const float*)d_in[2];
  float* out = (float*)d_out;
  float* ws  = (float*)d_ws;

  float* xn   = ws;                                  // B*C*NPIX
  float* soft = xn   + (size_t)BB * CC * NPIX;       // B*K*NPIX
  float* fs   = soft + (size_t)BB * KK * NPIX;       // B*K*NP
  float* ghat = fs   + (size_t)BB * KK * NP;         // B*K*C
  float* ssq  = ghat + (size_t)BB * KK * CC;         // B*K*NP
  float* sp   = ssq  + (size_t)BB * KK * NP;         // B*K*NCG*NP

  k_norm_soft<<<dim3(HH, BB), 512, 0, stream>>>(x, convw, xn, soft);
  k_global<<<dim3(KK, BB), 256, 0, stream>>>(xn, soft, cent, ghat);
  k_global2<<<dim3(BB), 256, 0, stream>>>(ghat, out + (size_t)BB * KK * CC * NP);
  k_local3<0><<<dim3(NCG, KK / 8, BB * 4), 320, 0, stream>>>(xn, soft, cent, sp, fs, out);
  k_nf_a<<<dim3((BB * KK * NP + 255) / 256), 256, 0, stream>>>(sp, ssq);
  k_nf_b<<<dim3((NP + 3) / 4, BB), 256, 0, stream>>>(ssq, fs);
  k_local3<1><<<dim3(NCG, KK / 8, BB * 4), 320, 0, stream>>>(xn, soft, cent, sp, fs, out);
}

// Round 6
// 442.325 us; speedup vs baseline: 1.1910x; 1.1910x over previous
//
#include <hip/hip_runtime.h>
#include <math.h>

#define BB 2
#define CC 512
#define HH 30
#define WW 40
#define KK 64
#define NPIX (HH*WW)
#define HP 27
#define WP 37
#define NP (HP*WP)
#define LEPS 1e-12f
#define NCG 16        // c-groups (32 c each)

// ---------------------------------------------------------------------------
// Kernel 1: per-(b,h) row: channel L2-norm, xn store, logits (K=64) + softmax.
// ---------------------------------------------------------------------------
__global__ __launch_bounds__(512) void k_norm_soft(
    const float* __restrict__ x, const float* __restrict__ convw,
    float* __restrict__ xn, float* __restrict__ soft)
{
  const int h = blockIdx.x, b = blockIdx.y;
  const int t = threadIdx.x;
  __shared__ float xc[64][41];
  __shared__ float cw[64][65];
  __shared__ float Lb[KK][WW + 1];
  __shared__ float psum[12][WW];
  __shared__ float invn[WW];
  __shared__ float mx[WW], Zs[WW];

  const size_t xbase = (size_t)b * CC * NPIX + (size_t)h * WW;

  if (t < 480) {
    const int w = t % 40, part = t / 40;
    float s = 0.f;
    for (int c = part; c < CC; c += 12) {
      const float v = x[xbase + (size_t)c * NPIX + w];
      s = fmaf(v, v, s);
    }
    psum[part][w] = s;
  }
  __syncthreads();
  if (t < 40) {
    float s = 0.f;
    #pragma unroll
    for (int p = 0; p < 12; ++p) s += psum[p][t];
    invn[t] = 1.f / fmaxf(sqrtf(s), LEPS);
  }
  __syncthreads();

  const int k = t & 63, wp = t >> 6;
  float acc[5] = {0.f, 0.f, 0.f, 0.f, 0.f};
  for (int cb = 0; cb < CC; cb += 64) {
    #pragma unroll
    for (int n = 0; n < 5; ++n) {
      const int idx = t + 512 * n;
      const int c = idx / 40, w = idx % 40;
      const float v = x[xbase + (size_t)(cb + c) * NPIX + w] * invn[w];
      xc[c][w] = v;
      xn[xbase + (size_t)(cb + c) * NPIX + w] = v;
    }
    #pragma unroll
    for (int n = 0; n < 8; ++n) {
      const int idx = t + 512 * n;
      const int kk2 = idx >> 6, c2 = idx & 63;
      cw[kk2][c2] = convw[(size_t)kk2 * CC + cb + c2];
    }
    __syncthreads();
    #pragma unroll 1
    for (int c = 0; c < 64; ++c) {
      const float cv = cw[k][c];
      #pragma unroll
      for (int n = 0; n < 5; ++n)
        acc[n] = fmaf(cv, xc[c][wp + 8 * n], acc[n]);
    }
    __syncthreads();
  }
  #pragma unroll
  for (int n = 0; n < 5; ++n) Lb[k][wp + 8 * n] = acc[n];
  __syncthreads();
  if (t < 40) {
    float m = -1e30f;
    for (int kk2 = 0; kk2 < KK; ++kk2) m = fmaxf(m, Lb[kk2][t]);
    float Z = 0.f;
    for (int kk2 = 0; kk2 < KK; ++kk2) Z += expf(Lb[kk2][t] - m);
    mx[t] = m; Zs[t] = Z;
  }
  __syncthreads();
  const size_t sbase = (size_t)b * KK * NPIX + (size_t)h * WW;
  #pragma unroll
  for (int n = 0; n < 5; ++n) {
    const int idx = t + 512 * n;
    const int kk2 = idx / 40, w = idx % 40;
    soft[sbase + (size_t)kk2 * NPIX + w] = expf(Lb[kk2][w] - mx[w]) / Zs[w];
  }
}

// ---------------------------------------------------------------------------
// Kernel G: per-(b,k) global VLAD row, first L2 norm over c.
// ---------------------------------------------------------------------------
__global__ __launch_bounds__(256) void k_global(
    const float* __restrict__ xn, const float* __restrict__ soft,
    const float* __restrict__ cent, float* __restrict__ ghat)
{
  const int k = blockIdx.x, b = blockIdx.y, t = threadIdx.x;
  __shared__ float sb[NPIX];
  __shared__ float red[256];
  const float* srow = soft + ((size_t)b * KK + k) * NPIX;
  for (int i2 = t; i2 < NPIX; i2 += 256) sb[i2] = srow[i2];
  __syncthreads();
  float p = 0.f;
  for (int i2 = t; i2 < NPIX; i2 += 256) p += sb[i2];
  red[t] = p;
  __syncthreads();
  for (int s = 128; s > 0; s >>= 1) { if (t < s) red[t] += red[t + s]; __syncthreads(); }
  const float Sg = red[0];
  __syncthreads();

  const int c0 = t, c1 = t + 256;
  const float* x0 = xn + ((size_t)b * CC + c0) * NPIX;
  const float* x1 = xn + ((size_t)b * CC + c1) * NPIX;
  float a0 = 0.f, a1 = 0.f;
  for (int p4 = 0; p4 < NPIX; p4 += 4) {
    const float4 s4 = *(const float4*)&sb[p4];
    const float4 v0 = *(const float4*)(x0 + p4);
    const float4 v1 = *(const float4*)(x1 + p4);
    a0 = fmaf(s4.x, v0.x, a0); a0 = fmaf(s4.y, v0.y, a0);
    a0 = fmaf(s4.z, v0.z, a0); a0 = fmaf(s4.w, v0.w, a0);
    a1 = fmaf(s4.x, v1.x, a1); a1 = fmaf(s4.y, v1.y, a1);
    a1 = fmaf(s4.z, v1.z, a1); a1 = fmaf(s4.w, v1.w, a1);
  }
  const float g0 = a0 - cent[(size_t)k * CC + c0] * Sg;
  const float g1 = a1 - cent[(size_t)k * CC + c1] * Sg;
  red[t] = g0 * g0 + g1 * g1;
  __syncthreads();
  for (int s = 128; s > 0; s >>= 1) { if (t < s) red[t] += red[t + s]; __syncthreads(); }
  const float inv = 1.f / fmaxf(sqrtf(red[0]), LEPS);
  float* gr = ghat + ((size_t)b * KK + k) * CC;
  gr[c0] = g0 * inv; gr[c1] = g1 * inv;
}

__global__ __launch_bounds__(256) void k_global2(
    const float* __restrict__ ghat, float* __restrict__ outg)
{
  const int b = blockIdx.x, t = threadIdx.x;
  __shared__ float red[256];
  const float* gb = ghat + (size_t)b * KK * CC;
  float p = 0.f;
  for (int i2 = t; i2 < KK * CC; i2 += 256) { const float v = gb[i2]; p = fmaf(v, v, p); }
  red[t] = p;
  __syncthreads();
  for (int s = 128; s > 0; s >>= 1) { if (t < s) red[t] += red[t + s]; __syncthreads(); }
  const float inv = 1.f / fmaxf(sqrtf(red[0]), LEPS);
  for (int i2 = t; i2 < KK * CC; i2 += 256)
    outg[(size_t)b * KK * CC + i2] = gb[i2] * inv;
}

// ---------------------------------------------------------------------------
// Kernel L v7: block = (cg 32c, kg 4k, b x i-block of <=4 rows). BARRIER-FREE
// main loop: full 7-row xn slab + soft slab staged once (read-only), one
// syncthreads, then independent rows -> compiler pipelines across rows.
// Tile 4c x 4k x 1j, acc=16, no spills (cap 170 VGPR at (320,3)).
// PHASE 0 map t=(c8 + 8j): shfl_xor c-octet reduce -> sp partials.
// PHASE 1 map t=(j + 40c8): 40-consecutive-j coalesced out stores.
// ---------------------------------------------------------------------------
template<int PHASE>
__global__ __launch_bounds__(320, 3) void k_local4(
    const float* __restrict__ xn, const float* __restrict__ soft,
    const float* __restrict__ cent, float* __restrict__ sp,
    const float* __restrict__ fs, float* __restrict__ out)
{
  const int cg = blockIdx.x;             // 0..15 (32 c)
  const int kg = blockIdx.y;             // 0..15 (4 k)
  const int bz = blockIdx.z;             // b*7 + iq
  const int b = bz / 7, iq = bz % 7;
  const int i0 = iq * 4;
  const int n_i = (iq == 6) ? 3 : 4;
  const int k0 = kg * 4, c0 = cg * 32;
  const int t = threadIdx.x;

  __shared__ float xn_l[32][280];        // [c][row_l*40 + w], stride 280 (2-way banks, free)
  __shared__ float soft_l[4][280];
  __shared__ float cent_l[4][32];

  // stage xn slab rows i0..i0+6 (clamped), coalesced float4
  for (int u = t; u < 2240; u += 320) {
    const int c = u / 70, rem = u % 70;
    const int rl = rem / 10, q = rem % 10;
    int row = i0 + rl; if (row > HH - 1) row = HH - 1;
    *(float4*)&xn_l[c][rl * 40 + q * 4] =
      *(const float4*)&xn[((size_t)(b * CC + c0 + c)) * NPIX + (size_t)row * 40 + q * 4];
  }
  if (t < 280) {
    const int kk = t / 70, rem = t % 70;
    const int rl = rem / 10, q = rem % 10;
    int row = i0 + rl; if (row > HH - 1) row = HH - 1;
    *(float4*)&soft_l[kk][rl * 40 + q * 4] =
      *(const float4*)&soft[((size_t)(b * KK + k0 + kk)) * NPIX + (size_t)row * 40 + q * 4];
  }
  if (t < 128) cent_l[t >> 5][t & 31] = cent[(size_t)(k0 + (t >> 5)) * CC + c0 + (t & 31)];
  __syncthreads();

  const int c8 = (PHASE == 0) ? (t & 7) : (t / 40);
  const int j  = (PHASE == 0) ? (t >> 3) : (t % 40);

  for (int ii = 0; ii < n_i; ++ii) {
    const int i = i0 + ii;
    float acc[4][4];
    float Ssum[4] = {0.f, 0.f, 0.f, 0.f};
    #pragma unroll
    for (int cc = 0; cc < 4; ++cc)
      #pragma unroll
      for (int kk = 0; kk < 4; ++kk) acc[cc][kk] = 0.f;

    #pragma unroll
    for (int r = 0; r < 4; ++r) {
      const int base = (ii + r) * 40 + j;
      float sv[4][4], xv[4][4];
      #pragma unroll
      for (int kk = 0; kk < 4; ++kk)
        #pragma unroll
        for (int dx = 0; dx < 4; ++dx) sv[kk][dx] = soft_l[kk][base + dx];
      #pragma unroll
      for (int cc = 0; cc < 4; ++cc)
        #pragma unroll
        for (int dx = 0; dx < 4; ++dx) xv[cc][dx] = xn_l[cc * 8 + c8][base + dx];
      #pragma unroll
      for (int kk = 0; kk < 4; ++kk)
        Ssum[kk] += (sv[kk][0] + sv[kk][1]) + (sv[kk][2] + sv[kk][3]);
      #pragma unroll
      for (int cc = 0; cc < 4; ++cc)
        #pragma unroll
        for (int kk = 0; kk < 4; ++kk) {
          float a = acc[cc][kk];
          a = fmaf(xv[cc][0], sv[kk][0], a);
          a = fmaf(xv[cc][1], sv[kk][1], a);
          a = fmaf(xv[cc][2], sv[kk][2], a);
          a = fmaf(xv[cc][3], sv[kk][3], a);
          acc[cc][kk] = a;
        }
    }

    if (PHASE == 0) {
      #pragma unroll
      for (int kk = 0; kk < 4; ++kk) {
        float s = 0.f;
        #pragma unroll
        for (int cc = 0; cc < 4; ++cc) {
          const float raw = fmaf(-cent_l[kk][cc * 8 + c8], Ssum[kk], acc[cc][kk]);
          s = fmaf(raw, raw, s);
        }
        s += __shfl_xor(s, 1, 64);
        s += __shfl_xor(s, 2, 64);
        s += __shfl_xor(s, 4, 64);
        if (c8 == 0 && j < WP)
          sp[(((size_t)(b * KK + k0 + kk)) * NCG + cg) * NP + (size_t)i * WP + j] = s;
      }
    } else if (j < WP) {
      float fsv[4];
      #pragma unroll
      for (int kk = 0; kk < 4; ++kk)
        fsv[kk] = fs[((size_t)(b * KK + k0 + kk)) * NP + (size_t)i * WP + j];
      #pragma unroll
      for (int kk = 0; kk < 4; ++kk)
        #pragma unroll
        for (int cc = 0; cc < 4; ++cc) {
          const float raw = fmaf(-cent_l[kk][cc * 8 + c8], Ssum[kk], acc[cc][kk]);
          out[((size_t)((b * KK + k0 + kk) * CC + c0 + cc * 8 + c8)) * NP
              + (size_t)i * WP + j] = raw * fsv[kk];
        }
    }
  }
}

// ---------------------------------------------------------------------------
// Kernel NF: per (b, 4 pixels): sum the 16 c-group partials, build the exact
// per-(b,k,p) scale with a 64-way LDS reduce for the cross-k second norm.
// ---------------------------------------------------------------------------
__global__ __launch_bounds__(256) void k_nf(
    const float* __restrict__ sp, float* __restrict__ fs)
{
  const int b = blockIdx.y, t = threadIdx.x;
  const int k = t >> 2, dp = t & 3;
  const int p = blockIdx.x * 4 + dp;
  __shared__ float red[64][4];
  __shared__ float inv2s[4];
  const bool ok = p < NP;
  float sr = 0.f;
  if (ok) {
    #pragma unroll
    for (int g = 0; g < NCG; ++g)
      sr += sp[(((size_t)(b * KK + k)) * NCG + g) * NP + p];
  }
  const float iv = 1.f / fmaxf(sqrtf(sr) * 0.0625f, LEPS);
  red[k][dp] = sr * (1.f / 256.f) * iv * iv;
  __syncthreads();
  if (t < 4) {
    float s = 0.f;
    #pragma unroll
    for (int kk = 0; kk < 64; ++kk) s += red[kk][t];
    inv2s[t] = 1.f / fmaxf(sqrtf(s), LEPS);
  }
  __syncthreads();
  if (ok)
    fs[((size_t)(b * KK + k)) * NP + p] = 0.0625f * iv * inv2s[dp];
}

// ---------------------------------------------------------------------------
extern "C" void kernel_launch(void* const* d_in, const int* in_sizes, int n_in,
                              void* d_out, int out_size, void* d_ws, size_t ws_size,
                              hipStream_t stream)
{
  const float* x     = (const float*)d_in[0];
  const float* convw = (const float*)d_in[1];
  const float* cent  = (const float*)d_in[2];
  float* out = (float*)d_out;
  float* ws  = (float*)d_ws;

  float* xn   = ws;                                  // B*C*NPIX
  float* soft = xn   + (size_t)BB * CC * NPIX;       // B*K*NPIX
  float* fs   = soft + (size_t)BB * KK * NPIX;       // B*K*NP
  float* ghat = fs   + (size_t)BB * KK * NP;         // B*K*C
  float* sp   = ghat + (size_t)BB * KK * CC;         // B*K*NCG*NP

  k_norm_soft<<<dim3(HH, BB), 512, 0, stream>>>(x, convw, xn, soft);
  k_global<<<dim3(KK, BB), 256, 0, stream>>>(xn, soft, cent, ghat);
  k_global2<<<dim3(BB), 256, 0, stream>>>(ghat, out + (size_t)BB * KK * CC * NP);
  k_local4<0><<<dim3(NCG, KK / 4, BB * 7), 320, 0, stream>>>(xn, soft, cent, sp, fs, out);
  k_nf<<<dim3((NP + 3) / 4, BB), 256, 0, stream>>>(sp, fs);
  k_local4<1><<<dim3(NCG, KK / 4, BB * 7), 320, 0, stream>>>(xn, soft, cent, sp, fs, out);
}